// Round 9
// baseline (354.060 us; speedup 1.0000x reference)
//
#include <hip/hip_runtime.h>
#include <math.h>

#define D_MODEL 1024
#define HIDDEN  2048
#define D_STATE 16
#define BATCH   2
#define SEQ     2048
#define NTOK    (BATCH*SEQ)   // 4096
#define CHUNK   32
#define NCHUNK  (SEQ/CHUNK)   // 64

typedef __attribute__((ext_vector_type(8))) short bf16x8;
typedef __attribute__((ext_vector_type(8))) unsigned short ushort8;
typedef __attribute__((ext_vector_type(4))) float f32x4;

#define GLOAD_LDS16(gptr, lptr) \
    __builtin_amdgcn_global_load_lds((const __attribute__((address_space(1))) void*)(gptr), \
                                     (__attribute__((address_space(3))) void*)(lptr), 16, 0, 0)

__device__ __forceinline__ float softplus_f(float x) {
    return fmaxf(x, 0.0f) + log1pf(expf(-fabsf(x)));
}
__device__ __forceinline__ float sigmoid_f(float x) {
    return 1.0f / (1.0f + expf(-x));
}
__device__ __forceinline__ ushort f2bf(float f) {      // RNE fp32->bf16
    unsigned u = __float_as_uint(f);
    unsigned r = (u + 0x7fffu + ((u >> 16) & 1u)) >> 16;
    return (ushort)r;
}
__device__ __forceinline__ float bf2f(ushort u) {
    return __uint_as_float(((unsigned)u) << 16);
}

// Converts x, W_x, W_g, W_dt, W_out into a contiguous bf16 arena.
// Block 0 also zeroes dt_sum (replaces the hipMemsetAsync dispatch).
__global__ __launch_bounds__(256) void cvt_all(
    const float* __restrict__ x, const float* __restrict__ Wx,
    const float* __restrict__ Wg, const float* __restrict__ Wdt,
    const float* __restrict__ Wout, ushort* __restrict__ arena,
    float* __restrict__ dt_sum)
{
    if (blockIdx.x == 0) {
        float4 z = {0.f, 0.f, 0.f, 0.f};
        reinterpret_cast<float4*>(dt_sum)[threadIdx.x]       = z;
        reinterpret_cast<float4*>(dt_sum)[256 + threadIdx.x] = z;   // 2048 floats
    }
    int i = blockIdx.x * 256 + threadIdx.x;   // float4 index, total 3145728
    const float* src; int base;
    if      (i < 1048576) { src = x;    base = 0; }
    else if (i < 1572864) { src = Wx;   base = 1048576; }
    else if (i < 2097152) { src = Wg;   base = 1572864; }
    else if (i < 2621440) { src = Wdt;  base = 2097152; }
    else                  { src = Wout; base = 2621440; }
    float4 v = reinterpret_cast<const float4*>(src)[i - base];
    ushort4 o = { f2bf(v.x), f2bf(v.y), f2bf(v.z), f2bf(v.w) };
    reinterpret_cast<ushort4*>(arena)[i] = o;
}

// ---------------------------------------------------------------------------
// Fused projection GEMM (R9): A via LDS pipe3 (3x8KB bufs), B-fragments
// DIRECT FROM GLOBAL (L2) into double-buffered registers.
// Rationale: R3 profile (MfmaUtil 23%, VALUBusy 53%) matches an LDS-pipe
// bound: 8 ds_read_b128 (~96cy, one shared LDS pipe/CU) vs 16 MFMA (~78cy
// matrix pipe) per wave per K-step. B rows are L2-resident (256KB panel,
// reused by 32 m-blocks); reading them as per-lane global bf16x8 (16-row x
// 64B segments, 16B aligned) halves LDS reads AND staging, and shrinks loop
// LDS to 24KB (block 32KB) -> ~4 blocks/CU (was 2).
// vmcnt trace: per iter issue [stageA(t+2)]x2 then [loadB(t+1)]x4.
//   Top of iter t queue: A(t+1):2, B(t):4 (older drained by prior waits);
//   vmcnt(6)+compiler's B-use wait guarantee A(t) resident before barrier.
//   lgkmcnt(0) before barrier: own ds_reads of t-1 done -> staging can't race.
// A-side k-chunk XOR swizzle kept; B needs none (global loads don't conflict).
// ---------------------------------------------------------------------------
__global__ __launch_bounds__(256) void proj_gemm_fused(
    const ushort* __restrict__ xbf, const ushort* __restrict__ Wcat,
    const float* __restrict__ b_x, const float* __restrict__ b_g,
    const float* __restrict__ b_dt, ushort* __restrict__ u_out,
    ushort* __restrict__ g_out, float* __restrict__ dt_sum)
{
    __shared__ ushort S[16384];            // 32KB: loop uses 24KB (3x8KB A); epi Cs 32KB
    ushort* As = S;
    const int tid = threadIdx.x, lane = tid & 63, w = tid >> 6;
    const int wm = w & 1, wn = w >> 1;
    const int m0 = blockIdx.x * 128, n0 = blockIdx.y * 128;   // m-fast
    const int quad = lane >> 4, fr = lane & 15;
    const int lr   = lane >> 2;
    const int qsrc = (lane & 3) ^ ((lane >> 3) & 3);   // pre-swizzled A src chunk
    const int chq  = quad ^ ((fr >> 1) & 3);           // swizzled A read chunk
    const int K = D_MODEL;

    // A staging: wave w covers rows w*32..w*32+31 (2 loads of 16 rows)
    const size_t ga0 = (size_t)(m0 + w * 32 + lr) * K + qsrc * 8;
    const size_t ga1 = ga0 + (size_t)16 * K;
    // B global fragment bases (bf16x8 per lane): row n0+wn*64+j*16+fr, k quad*8
    const size_t gb0 = (size_t)(n0 + wn * 64 +  0 + fr) * K + quad * 8;
    const size_t gb1 = (size_t)(n0 + wn * 64 + 16 + fr) * K + quad * 8;
    const size_t gb2 = (size_t)(n0 + wn * 64 + 32 + fr) * K + quad * 8;
    const size_t gb3 = (size_t)(n0 + wn * 64 + 48 + fr) * K + quad * 8;

    f32x4 acc[4][4];
    #pragma unroll
    for (int i = 0; i < 4; i++)
        #pragma unroll
        for (int j = 0; j < 4; j++)
            acc[i][j] = (f32x4){0.f, 0.f, 0.f, 0.f};

#define PJ_LOADB(d0, d1, d2, d3, T) do {                                          \
    const size_t kb_ = ((T) < 32) ? (size_t)(T) * 32 : 0;                         \
    d0 = *reinterpret_cast<const bf16x8*>(&Wcat[gb0 + kb_]);                      \
    d1 = *reinterpret_cast<const bf16x8*>(&Wcat[gb1 + kb_]);                      \
    d2 = *reinterpret_cast<const bf16x8*>(&Wcat[gb2 + kb_]);                      \
    d3 = *reinterpret_cast<const bf16x8*>(&Wcat[gb3 + kb_]);                      \
  } while (0)

#define PJ_STAGEA(T, BUFP) do {                                                   \
    const size_t ko_ = ((T) < 32) ? (size_t)(T) * 32 : 0;                         \
    GLOAD_LDS16(xbf + ga0 + ko_, (BUFP) + w * 1024);                              \
    GLOAD_LDS16(xbf + ga1 + ko_, (BUFP) + w * 1024 + 512);                        \
  } while (0)

#define PJ_BODY(ABUF, B0, B1, B2, B3) do {                                        \
    bf16x8 af0 = *reinterpret_cast<const bf16x8*>(&(ABUF)[(wm*64 +  0 + fr)*32 + chq*8]); \
    bf16x8 af1 = *reinterpret_cast<const bf16x8*>(&(ABUF)[(wm*64 + 16 + fr)*32 + chq*8]); \
    bf16x8 af2 = *reinterpret_cast<const bf16x8*>(&(ABUF)[(wm*64 + 32 + fr)*32 + chq*8]); \
    bf16x8 af3 = *reinterpret_cast<const bf16x8*>(&(ABUF)[(wm*64 + 48 + fr)*32 + chq*8]); \
    acc[0][0]=__builtin_amdgcn_mfma_f32_16x16x32_bf16(af0,B0,acc[0][0],0,0,0);    \
    acc[0][1]=__builtin_amdgcn_mfma_f32_16x16x32_bf16(af0,B1,acc[0][1],0,0,0);    \
    acc[0][2]=__builtin_amdgcn_mfma_f32_16x16x32_bf16(af0,B2,acc[0][2],0,0,0);    \
    acc[0][3]=__builtin_amdgcn_mfma_f32_16x16x32_bf16(af0,B3,acc[0][3],0,0,0);    \
    acc[1][0]=__builtin_amdgcn_mfma_f32_16x16x32_bf16(af1,B0,acc[1][0],0,0,0);    \
    acc[1][1]=__builtin_amdgcn_mfma_f32_16x16x32_bf16(af1,B1,acc[1][1],0,0,0);    \
    acc[1][2]=__builtin_amdgcn_mfma_f32_16x16x32_bf16(af1,B2,acc[1][2],0,0,0);    \
    acc[1][3]=__builtin_amdgcn_mfma_f32_16x16x32_bf16(af1,B3,acc[1][3],0,0,0);    \
    acc[2][0]=__builtin_amdgcn_mfma_f32_16x16x32_bf16(af2,B0,acc[2][0],0,0,0);    \
    acc[2][1]=__builtin_amdgcn_mfma_f32_16x16x32_bf16(af2,B1,acc[2][1],0,0,0);    \
    acc[2][2]=__builtin_amdgcn_mfma_f32_16x16x32_bf16(af2,B2,acc[2][2],0,0,0);    \
    acc[2][3]=__builtin_amdgcn_mfma_f32_16x16x32_bf16(af2,B3,acc[2][3],0,0,0);    \
    acc[3][0]=__builtin_amdgcn_mfma_f32_16x16x32_bf16(af3,B0,acc[3][0],0,0,0);    \
    acc[3][1]=__builtin_amdgcn_mfma_f32_16x16x32_bf16(af3,B1,acc[3][1],0,0,0);    \
    acc[3][2]=__builtin_amdgcn_mfma_f32_16x16x32_bf16(af3,B2,acc[3][2],0,0,0);    \
    acc[3][3]=__builtin_amdgcn_mfma_f32_16x16x32_bf16(af3,B3,acc[3][3],0,0,0);    \
  } while (0)

    // prologue: A0 -> buf0, A1 -> buf1, B0 -> bA regs
    PJ_STAGEA(0, As);
    PJ_STAGEA(1, As + 4096);
    bf16x8 bA0, bA1, bA2, bA3, bB0, bB1, bB2, bB3;
    PJ_LOADB(bA0, bA1, bA2, bA3, 0);

    ushort* Asb0 = As;            // buffer holding tile t
    ushort* Asb1 = As + 4096;     // tile t+1
    ushort* Asb2 = As + 8192;     // staging target for t+2
    #pragma unroll 1
    for (int t = 0; t < 32; t += 2) {
        // ---- even tile t: compute with bA, prefetch B(t+1)->bB ----
        asm volatile("s_waitcnt vmcnt(6) lgkmcnt(0)" ::: "memory");
        asm volatile("s_barrier" ::: "memory");
        PJ_STAGEA(t + 2, Asb2);
        PJ_LOADB(bB0, bB1, bB2, bB3, t + 1);
        PJ_BODY(Asb0, bA0, bA1, bA2, bA3);

        // ---- odd tile t+1: compute with bB, prefetch B(t+2)->bA ----
        asm volatile("s_waitcnt vmcnt(6) lgkmcnt(0)" ::: "memory");
        asm volatile("s_barrier" ::: "memory");
        PJ_STAGEA(t + 3, Asb0);   // (t+3)%3 == t%3; tile t reads done above
        PJ_LOADB(bA0, bA1, bA2, bA3, t + 2);
        PJ_BODY(Asb1, bB0, bB1, bB2, bB3);

        // rotate: next even tile t+2 lives in Asb2
        ushort* tmp = Asb0; Asb0 = Asb2; Asb2 = Asb1; Asb1 = tmp;
    }
    asm volatile("s_waitcnt vmcnt(0) lgkmcnt(0)" ::: "memory");
    asm volatile("s_barrier" ::: "memory");
#undef PJ_BODY
#undef PJ_STAGEA
#undef PJ_LOADB

    const int region = n0 >> 11;           // 0:u 1:g 2:dt
    const int ncb = n0 & 2047;

    if (region == 2) {
        #pragma unroll
        for (int j = 0; j < 4; j++) {
            int n = ncb + wn * 64 + j * 16 + fr;
            float bj = b_dt[n];
            float s = 0.f;
            #pragma unroll
            for (int i = 0; i < 4; i++)
                #pragma unroll
                for (int r = 0; r < 4; r++)
                    s += softplus_f(acc[i][j][r] + bj);
            s += __shfl_xor(s, 16);
            s += __shfl_xor(s, 32);
            if (lane < 16) atomicAdd(&dt_sum[n], s);
        }
    } else {
        const float* bias = region ? b_g : b_x;
        ushort* out = region ? g_out : u_out;
        ushort* Cs = S;                    // [128][128] bf16 = 32KB
        #pragma unroll
        for (int j = 0; j < 4; j++) {
            int col = wn * 64 + j * 16 + fr;
            float bj = bias[ncb + col];
            #pragma unroll
            for (int i = 0; i < 4; i++) {
                int row = wm * 64 + i * 16 + quad * 4;
                #pragma unroll
                for (int r = 0; r < 4; r++) {
                    float v = acc[i][j][r] + bj;
                    if (region) v = sigmoid_f(v);
                    Cs[(row + r) * 128 + col] = f2bf(v);
                }
            }
        }
        __syncthreads();
        #pragma unroll
        for (int k = 0; k < 8; k++) {
            int v = k * 256 + tid;
            int row = v >> 4, c = (v & 15) * 8;
            *reinterpret_cast<ushort8*>(&out[(size_t)(m0 + row) * HIDDEN + ncb + c]) =
                *reinterpret_cast<const ushort8*>(&Cs[v * 8]);
        }
    }
}

// ---------------------------------------------------------------------------
// Out projection, 64x128 tile, BK=64, pipe3 (3 bufs, vmcnt(6)). m-fast grid.
// Unchanged (R3-proven) -- B->regs port deferred for attribution.
// ---------------------------------------------------------------------------
__global__ __launch_bounds__(256) void gemm_out64(
    const ushort* __restrict__ ybf, const ushort* __restrict__ Wout,
    const float* __restrict__ b_out, const float* __restrict__ x,
    float* __restrict__ resid)
{
    __shared__ ushort S[36864];            // 72KB: As 3x4096us | Bs 3x8192us
    ushort* As = S;
    ushort* Bs = S + 12288;
    const int tid = threadIdx.x, lane = tid & 63, w = tid >> 6;
    const int m0 = blockIdx.x * 64, n0 = blockIdx.y * 128;    // m-fast
    const int quad = lane >> 4, fr = lane & 15;
    const int lr8  = lane >> 3;                   // row-in-8 for staging
    const int q8   = (lane & 7) ^ (lr8 & 7);      // pre-swizzled src chunk
    const int K = HIDDEN;

    const size_t ga = (size_t)(m0 + w * 16 + lr8) * K + q8 * 8;
    const size_t gb = (size_t)(n0 + w * 32 + lr8) * K + q8 * 8;

    f32x4 acc[4][2];
    #pragma unroll
    for (int i = 0; i < 4; i++)
        #pragma unroll
        for (int j = 0; j < 2; j++)
            acc[i][j] = (f32x4){0.f, 0.f, 0.f, 0.f};

#define STAGE_OUT(KT, BUF) do {                                                   \
    const size_t ko_ = (size_t)(KT) * 64;                                         \
    GLOAD_LDS16(ybf  + ga + ko_,            &As[(BUF)*4096 + (w*2+0)*512]);       \
    GLOAD_LDS16(ybf  + ga + 8*K + ko_,      &As[(BUF)*4096 + (w*2+1)*512]);       \
    GLOAD_LDS16(Wout + gb + ko_,            &Bs[(BUF)*8192 + (w*4+0)*512]);       \
    GLOAD_LDS16(Wout + gb + 8*K + ko_,      &Bs[(BUF)*8192 + (w*4+1)*512]);       \
    GLOAD_LDS16(Wout + gb + 16*K + ko_,     &Bs[(BUF)*8192 + (w*4+2)*512]);       \
    GLOAD_LDS16(Wout + gb + 24*K + ko_,     &Bs[(BUF)*8192 + (w*4+3)*512]);       \
  } while (0)

    STAGE_OUT(0, 0);
    STAGE_OUT(1, 1);

    int buf = 0;
    for (int t = 0; t < 32; t++) {
        asm volatile("s_waitcnt vmcnt(6) lgkmcnt(0)" ::: "memory");
        asm volatile("s_barrier" ::: "memory");
        int nb = buf + 2; if (nb >= 3) nb -= 3;
        const int kt = (t + 2 < 32) ? (t + 2) : 0;    // dummy past end
        STAGE_OUT(kt, nb);

        const ushort* as = &As[buf * 4096];
        const ushort* bs = &Bs[buf * 8192];
        #pragma unroll
        for (int ks = 0; ks < 2; ks++) {
            const int ch = ((ks * 4 + quad) ^ (fr & 7)) * 8;
            bf16x8 af[4], bfv[2];
            #pragma unroll
            for (int mi = 0; mi < 4; mi++)
                af[mi] = *reinterpret_cast<const bf16x8*>(&as[(mi * 16 + fr) * 64 + ch]);
            #pragma unroll
            for (int nj = 0; nj < 2; nj++)
                bfv[nj] = *reinterpret_cast<const bf16x8*>(&bs[(w * 32 + nj * 16 + fr) * 64 + ch]);
            #pragma unroll
            for (int mi = 0; mi < 4; mi++)
                #pragma unroll
                for (int nj = 0; nj < 2; nj++)
                    acc[mi][nj] = __builtin_amdgcn_mfma_f32_16x16x32_bf16(af[mi], bfv[nj], acc[mi][nj], 0, 0, 0);
        }
        buf = (buf == 2) ? 0 : buf + 1;
    }
    asm volatile("s_waitcnt vmcnt(0) lgkmcnt(0)" ::: "memory");
    asm volatile("s_barrier" ::: "memory");
#undef STAGE_OUT

    float* Sf = (float*)S;                  // [64][128] f32 = 32KB (fits 72KB)
    #pragma unroll
    for (int nj = 0; nj < 2; nj++) {
        int col = w * 32 + nj * 16 + fr;
        float bj = b_out[n0 + col];
        #pragma unroll
        for (int mi = 0; mi < 4; mi++) {
            int row = mi * 16 + quad * 4;
            #pragma unroll
            for (int r = 0; r < 4; r++)
                Sf[(row + r) * 128 + col] = acc[mi][nj][r] + bj;
        }
    }
    __syncthreads();
    #pragma unroll
    for (int k = 0; k < 8; k++) {
        int v = k * 256 + tid;                 // float4 id, 0..2047
        int row = v >> 5, c = (v & 31) * 4;
        size_t off = (size_t)(m0 + row) * D_MODEL + n0 + c;
        float4 xa = *reinterpret_cast<const float4*>(&x[off]);
        float4 cv = *reinterpret_cast<const float4*>(&Sf[v * 4]);
        float4 o = { cv.x + xa.x, cv.y + xa.y, cv.z + xa.z, cv.w + xa.w };
        *reinterpret_cast<float4*>(&resid[off]) = o;
    }
}

__global__ __launch_bounds__(256) void dt_finalize(
    const float* __restrict__ dt_sum, const float* __restrict__ A_raw,
    const float* __restrict__ B_ssm, float* __restrict__ A_d,
    float* __restrict__ B_d, float* __restrict__ A_dL)
{
    int i = blockIdx.x * 256 + threadIdx.x;
    if (i >= HIDDEN * D_STATE) return;
    int h = i >> 4;
    float dt = dt_sum[h] * (1.0f / NTOK);
    dt = fminf(fmaxf(dt, 1e-3f), 2.0f);
    float Av = -softplus_f(A_raw[i]);
    float Ad = expf(Av * dt);
    float Bd = (Ad - 1.0f) / (Av + 1e-6f) * B_ssm[i];
    A_d[i] = Ad;
    B_d[i] = Bd;
    A_dL[i] = expf(Av * dt * CHUNK);
}

// Pass 1 (fused conv + gate + local scan): per-(b,chunk,h) thread.
__global__ __launch_bounds__(256) void scan_pass1(
    const ushort* __restrict__ u_bf, const ushort* __restrict__ g_bf,
    const float* __restrict__ conv_w, const float* __restrict__ conv_b,
    const float* __restrict__ A_d, const float* __restrict__ B_d,
    const float* __restrict__ C_ssm,
    ushort* __restrict__ ypart, float* __restrict__ states)
{
    int idx = blockIdx.x * 256 + threadIdx.x;
    int h  = idx & (HIDDEN - 1);
    int bc = idx >> 11;
    int c  = bc & (NCHUNK - 1);
    int b  = bc / NCHUNK;
    float Ad[D_STATE], Bd[D_STATE], Cv[D_STATE], st[D_STATE];
    const float4* a4 = reinterpret_cast<const float4*>(A_d  + h * D_STATE);
    const float4* b4 = reinterpret_cast<const float4*>(B_d  + h * D_STATE);
    const float4* c4 = reinterpret_cast<const float4*>(C_ssm + h * D_STATE);
    #pragma unroll
    for (int q = 0; q < 4; q++) {
        float4 av = a4[q], bv = b4[q], cv = c4[q];
        Ad[q*4+0]=av.x; Ad[q*4+1]=av.y; Ad[q*4+2]=av.z; Ad[q*4+3]=av.w;
        Bd[q*4+0]=bv.x; Bd[q*4+1]=bv.y; Bd[q*4+2]=bv.z; Bd[q*4+3]=bv.w;
        Cv[q*4+0]=cv.x; Cv[q*4+1]=cv.y; Cv[q*4+2]=cv.z; Cv[q*4+3]=cv.w;
    }
    #pragma unroll
    for (int s = 0; s < D_STATE; s++) st[s] = 0.f;

    float w0 = conv_w[h * 3 + 0], w1 = conv_w[h * 3 + 1];
    float w2 = conv_w[h * 3 + 2], cb = conv_b[h];
    const int tok0 = c * CHUNK;
    const size_t base = ((size_t)b * SEQ + tok0) * HIDDEN + h;
    float u_prev = (tok0 > 0) ? bf2f(u_bf[base - HIDDEN]) : 0.f;
    float u_cur  = bf2f(u_bf[base]);
    for (int l = 0; l < CHUNK; l++) {
        float u_next = (tok0 + l + 1 < SEQ) ? bf2f(u_bf[base + (size_t)(l + 1) * HIDDEN]) : 0.f;
        float gv = bf2f(g_bf[base + (size_t)l * HIDDEN]);
        float conv = u_prev * w0 + u_cur * w1 + u_next * w2 + cb;
        float uv = u_cur * gv + conv * (1.0f - gv);
        float y0 = 0.f, y1 = 0.f, y2 = 0.f, y3 = 0.f;
        #pragma unroll
        for (int s = 0; s < D_STATE; s += 4) {
            st[s+0] = fmaf(Ad[s+0], st[s+0], Bd[s+0] * uv);
            st[s+1] = fmaf(Ad[s+1], st[s+1], Bd[s+1] * uv);
            st[s+2] = fmaf(Ad[s+2], st[s+2], Bd[s+2] * uv);
            st[s+3] = fmaf(Ad[s+3], st[s+3], Bd[s+3] * uv);
            y0 = fmaf(st[s+0], Cv[s+0], y0);
            y1 = fmaf(st[s+1], Cv[s+1], y1);
            y2 = fmaf(st[s+2], Cv[s+2], y2);
            y3 = fmaf(st[s+3], Cv[s+3], y3);
        }
        ypart[base + (size_t)l * HIDDEN] = f2bf((y0 + y1) + (y2 + y3));
        u_prev = u_cur; u_cur = u_next;
    }
    float4* sp = reinterpret_cast<float4*>(states + ((size_t)bc * HIDDEN + h) * D_STATE);
    #pragma unroll
    for (int q = 0; q < 4; q++)
        sp[q] = (float4){st[q*4+0], st[q*4+1], st[q*4+2], st[q*4+3]};
}

// Pass 2: in-place exclusive propagation of chunk-boundary states.
// Batched 8-deep load prefetch: 8 independent loads in flight per group.
__global__ __launch_bounds__(256) void scan_pass2(
    float* __restrict__ states, const float* __restrict__ A_dL)
{
    int idx = blockIdx.x * 256 + threadIdx.x;
    int s = idx & 15;
    int h = (idx >> 4) & (HIDDEN - 1);
    int b = idx >> 15;
    float aL = A_dL[h * D_STATE + s];
    float carry = 0.f;
    const size_t cstride = (size_t)HIDDEN * D_STATE;
    float* p = states + ((size_t)b * NCHUNK * HIDDEN + h) * D_STATE + s;
    #pragma unroll 1
    for (int cb = 0; cb < NCHUNK / 8; cb++) {
        float fin[8];
        #pragma unroll
        for (int j = 0; j < 8; j++) fin[j] = p[(size_t)j * cstride];
        #pragma unroll
        for (int j = 0; j < 8; j++) {
            p[(size_t)j * cstride] = carry;
            carry = fmaf(aL, carry, fin[j]);
        }
        p += 8 * cstride;
    }
}

// Pass 3: y = ypart + sum_s C*A_d^(l+1)*s_in ; emit bf16 for the out-GEMM.
__global__ __launch_bounds__(256) void scan_pass3(
    const ushort* __restrict__ ypart, const float* __restrict__ states,
    const float* __restrict__ A_d, const float* __restrict__ C_ssm,
    ushort* __restrict__ ybf)
{
    int idx = blockIdx.x * 256 + threadIdx.x;
    int h  = idx & (HIDDEN - 1);
    int bc = idx >> 11;
    int c  = bc & (NCHUNK - 1);
    int b  = bc / NCHUNK;
    float Ad[D_STATE], t[D_STATE];
    const float* sp = states + ((size_t)bc * HIDDEN + h) * D_STATE;
    #pragma unroll
    for (int s = 0; s < D_STATE; s++) {
        float a = A_d[h * D_STATE + s];
        Ad[s] = a;
        t[s] = C_ssm[h * D_STATE + s] * a * sp[s];
    }
    const size_t base = ((size_t)b * SEQ + (size_t)c * CHUNK) * HIDDEN + h;
    for (int l = 0; l < CHUNK; l++) {
        float c0 = 0.f, c1 = 0.f;
        #pragma unroll
        for (int s = 0; s < D_STATE; s += 2) {
            c0 += t[s];
            c1 += t[s + 1];
            t[s] *= Ad[s];
            t[s + 1] *= Ad[s + 1];
        }
        ybf[base + (size_t)l * HIDDEN] = f2bf(bf2f(ypart[base + (size_t)l * HIDDEN]) + (c0 + c1));
    }
}

__global__ __launch_bounds__(256) void ln_kernel(
    const float* __restrict__ resid, const float* __restrict__ ln_g,
    const float* __restrict__ ln_b, float* __restrict__ out)
{
    int row = blockIdx.x;
    int tid = threadIdx.x;
    const float4 v = reinterpret_cast<const float4*>(resid + (size_t)row * D_MODEL)[tid];
    float s  = v.x + v.y + v.z + v.w;
    float ss = v.x * v.x + v.y * v.y + v.z * v.z + v.w * v.w;
    #pragma unroll
    for (int off = 32; off > 0; off >>= 1) {
        s  += __shfl_down(s, off);
        ss += __shfl_down(ss, off);
    }
    __shared__ float sbuf[4], ssbuf[4];
    int wid = tid >> 6, lane = tid & 63;
    if (lane == 0) { sbuf[wid] = s; ssbuf[wid] = ss; }
    __syncthreads();
    float tot  = sbuf[0] + sbuf[1] + sbuf[2] + sbuf[3];
    float tot2 = ssbuf[0] + ssbuf[1] + ssbuf[2] + ssbuf[3];
    float mean = tot * (1.0f / D_MODEL);
    float var  = tot2 * (1.0f / D_MODEL) - mean * mean;
    float rstd = rsqrtf(var + 1e-5f);
    const float4 gv = reinterpret_cast<const float4*>(ln_g)[tid];
    const float4 bv = reinterpret_cast<const float4*>(ln_b)[tid];
    float4 o;
    o.x = (v.x - mean) * rstd * gv.x + bv.x;
    o.y = (v.y - mean) * rstd * gv.y + bv.y;
    o.z = (v.z - mean) * rstd * gv.z + bv.z;
    o.w = (v.w - mean) * rstd * gv.w + bv.w;
    reinterpret_cast<float4*>(out + (size_t)row * D_MODEL)[tid] = o;
}

extern "C" void kernel_launch(void* const* d_in, const int* in_sizes, int n_in,
                              void* d_out, int out_size, void* d_ws, size_t ws_size,
                              hipStream_t stream) {
    const float* x      = (const float*)d_in[0];
    const float* W_x    = (const float*)d_in[1];
    const float* b_x    = (const float*)d_in[2];
    const float* W_g    = (const float*)d_in[3];
    const float* b_g    = (const float*)d_in[4];
    const float* conv_w = (const float*)d_in[5];
    const float* conv_b = (const float*)d_in[6];
    const float* A_raw  = (const float*)d_in[7];
    const float* B_ssm  = (const float*)d_in[8];
    const float* C_ssm  = (const float*)d_in[9];
    const float* W_dt   = (const float*)d_in[10];
    const float* b_dt   = (const float*)d_in[11];
    const float* W_out  = (const float*)d_in[12];
    const float* b_out  = (const float*)d_in[13];
    const float* ln_g   = (const float*)d_in[14];
    const float* ln_b   = (const float*)d_in[15];

    char* W = (char*)d_ws;
    ushort* arena   = (ushort*)(W);                    // 24MB: x_bf|Wcat|Wout_bf
    ushort* x_bf    = arena;                           // [4096,1024]
    ushort* Wcat    = arena + 4194304;                 // [6144,1024] (Wx|Wg|Wdt)
    ushort* Wout_bf = arena + 10485760;                // [1024,2048] (20..24MB)
    ushort* u_bf    = (ushort*)(W + (24ull << 20));    // 16MB [4096,2048] -> y_bf
    ushort* g_bf    = (ushort*)(W + (40ull << 20));    // 16MB [4096,2048]
    ushort* ypart   = (ushort*)(W + (56ull << 20));    // 16MB bf16 partial y
    float*  resid   = (float*)(W + (40ull << 20));     // 16MB, over g_bf (dead)
    // states: 16MB [B*NCHUNK,H,16] over x_bf+Wcat (0..16MB, dead after proj)
    float*  states  = (float*)(W);
    float*  dt_sum  = (float*)(W + (80ull << 20));     // 8KB
    float*  A_d     = (float*)(W + (80ull << 20) + 65536);
    float*  B_d     = (float*)(W + (80ull << 20) + 65536 + 131072);
    float*  A_dL    = (float*)(W + (80ull << 20) + 65536 + 262144);
    ushort* y_bf    = u_bf;                            // alias (u dead after pass1)

    dim3 blk(256);
    cvt_all<<<12288, blk, 0, stream>>>(x, W_x, W_g, W_dt, W_out, arena, dt_sum);

    dim3 grid_proj(NTOK / 128, 3 * HIDDEN / 128);   // (32 m, 48 n), m fastest
    proj_gemm_fused<<<grid_proj, blk, 0, stream>>>(x_bf, Wcat, b_x, b_g, b_dt,
                                                   u_bf, g_bf, dt_sum);
    dt_finalize<<<(HIDDEN * D_STATE) / 256, blk, 0, stream>>>(dt_sum, A_raw, B_ssm,
                                                              A_d, B_d, A_dL);
    scan_pass1<<<(BATCH * NCHUNK * HIDDEN) / 256, blk, 0, stream>>>(
        u_bf, g_bf, conv_w, conv_b, A_d, B_d, C_ssm, ypart, states);
    scan_pass2<<<(BATCH * HIDDEN * D_STATE) / 256, blk, 0, stream>>>(states, A_dL);
    scan_pass3<<<(BATCH * NCHUNK * HIDDEN) / 256, blk, 0, stream>>>(ypart, states, A_d,
                                                                    C_ssm, y_bf);
    dim3 grid_out(NTOK / 64, D_MODEL / 128);        // (64 m, 8 n), m fastest
    gemm_out64<<<grid_out, blk, 0, stream>>>(y_bf, Wout_bf, b_out, x, resid);
    ln_kernel<<<NTOK, blk, 0, stream>>>(resid, ln_g, ln_b, (float*)d_out);
}

// Round 10
// 282.199 us; speedup vs baseline: 1.2546x; 1.2546x over previous
//
#include <hip/hip_runtime.h>
#include <math.h>

#define D_MODEL 1024
#define HIDDEN  2048
#define D_STATE 16
#define BATCH   2
#define SEQ     2048
#define NTOK    (BATCH*SEQ)   // 4096
#define CHUNK   32
#define NCHUNK  (SEQ/CHUNK)   // 64

typedef __attribute__((ext_vector_type(8))) short bf16x8;
typedef __attribute__((ext_vector_type(8))) unsigned short ushort8;
typedef __attribute__((ext_vector_type(4))) float f32x4;

#define GLOAD_LDS16(gptr, lptr) \
    __builtin_amdgcn_global_load_lds((const __attribute__((address_space(1))) void*)(gptr), \
                                     (__attribute__((address_space(3))) void*)(lptr), 16, 0, 0)

__device__ __forceinline__ float softplus_f(float x) {
    return fmaxf(x, 0.0f) + log1pf(expf(-fabsf(x)));
}
__device__ __forceinline__ float sigmoid_f(float x) {
    return 1.0f / (1.0f + expf(-x));
}
__device__ __forceinline__ ushort f2bf(float f) {      // RNE fp32->bf16
    unsigned u = __float_as_uint(f);
    unsigned r = (u + 0x7fffu + ((u >> 16) & 1u)) >> 16;
    return (ushort)r;
}
__device__ __forceinline__ float bf2f(ushort u) {
    return __uint_as_float(((unsigned)u) << 16);
}

// Converts x, W_x, W_g, W_dt, W_out into a contiguous bf16 arena.
// Block 0 also zeroes dt_sum (replaces the hipMemsetAsync dispatch).
__global__ __launch_bounds__(256) void cvt_all(
    const float* __restrict__ x, const float* __restrict__ Wx,
    const float* __restrict__ Wg, const float* __restrict__ Wdt,
    const float* __restrict__ Wout, ushort* __restrict__ arena,
    float* __restrict__ dt_sum)
{
    if (blockIdx.x == 0) {
        float4 z = {0.f, 0.f, 0.f, 0.f};
        reinterpret_cast<float4*>(dt_sum)[threadIdx.x]       = z;
        reinterpret_cast<float4*>(dt_sum)[256 + threadIdx.x] = z;   // 2048 floats
    }
    int i = blockIdx.x * 256 + threadIdx.x;   // float4 index, total 3145728
    const float* src; int base;
    if      (i < 1048576) { src = x;    base = 0; }
    else if (i < 1572864) { src = Wx;   base = 1048576; }
    else if (i < 2097152) { src = Wg;   base = 1572864; }
    else if (i < 2621440) { src = Wdt;  base = 2097152; }
    else                  { src = Wout; base = 2621440; }
    float4 v = reinterpret_cast<const float4*>(src)[i - base];
    ushort4 o = { f2bf(v.x), f2bf(v.y), f2bf(v.z), f2bf(v.w) };
    reinterpret_cast<ushort4*>(arena)[i] = o;
}

// ---------------------------------------------------------------------------
// 3-stage pipelined 128x128 K-loop (4 waves), BK=32. Proven pipe3 schedule
// (R3/R8-measured: proj 92.3us, e2e 286.8us). LDS k-chunk XOR swizzle:
// LDS[row][c]=G[row][c^s(row)], s(row)=(row>>1)&3; staged via pre-swizzled
// source, read via chq.
// Session notes (mechanisms, do not retry):
//  - m97 full-drain (vmcnt(0)/iter): exposes load latency at 2 blocks/CU (R4).
//  - 256-wide tiles / 72-96KB LDS: co-residency loss beats density gain (R1,R5).
//  - XCD n-partition swizzle: breaks implicit m-slice A reuse, 3x FETCH (R7).
//  - B-fragments direct from global: 64-line gather per instr, 2.7x slower (R9).
// ---------------------------------------------------------------------------
__device__ __forceinline__ void kloop_pipe3(
    const ushort* __restrict__ A, const ushort* __restrict__ B,
    int K, int m0, int n0, ushort* As, ushort* Bs,
    f32x4 (&acc)[4][4], int lane, int w, int wm, int wn)
{
    const int lr   = lane >> 2;
    const int qsrc = (lane & 3) ^ ((lane >> 3) & 3);   // pre-swizzled src chunk
    const int kc   = qsrc * 8;
    const int quad = lane >> 4;
    const int fr   = lane & 15;
    const int chq  = quad ^ ((fr >> 1) & 3);           // swizzled read chunk

    const int slab0 = w * 2;
    const int r0 = slab0 * 16 + lr;
    const int r1 = r0 + 16;
    const size_t ga0 = (size_t)(m0 + r0) * K + kc;
    const size_t ga1 = (size_t)(m0 + r1) * K + kc;
    const size_t gb0 = (size_t)(n0 + r0) * K + kc;
    const size_t gb1 = (size_t)(n0 + r1) * K + kc;

    const int niter = K / 32;
    // prologue: sets 0 and 1
    GLOAD_LDS16(A + ga0,      &As[slab0 * 512]);
    GLOAD_LDS16(A + ga1,      &As[slab0 * 512 + 512]);
    GLOAD_LDS16(B + gb0,      &Bs[slab0 * 512]);
    GLOAD_LDS16(B + gb1,      &Bs[slab0 * 512 + 512]);
    GLOAD_LDS16(A + ga0 + 32, &As[4096 + slab0 * 512]);
    GLOAD_LDS16(A + ga1 + 32, &As[4096 + slab0 * 512 + 512]);
    GLOAD_LDS16(B + gb0 + 32, &Bs[4096 + slab0 * 512]);
    GLOAD_LDS16(B + gb1 + 32, &Bs[4096 + slab0 * 512 + 512]);

    int buf = 0;
    for (int i = 0; i < niter; i++) {
        // oldest 4 loads (this iter's tile) done; newest 4 may fly; all own
        // LDS reads (previous set) complete so prefetch can't race them.
        asm volatile("s_waitcnt vmcnt(4) lgkmcnt(0)" ::: "memory");
        asm volatile("s_barrier" ::: "memory");
        int nb = buf + 2; if (nb >= 3) nb -= 3;
        const size_t koff = (i + 2 < niter) ? (size_t)(i + 2) * 32 : 0;
        GLOAD_LDS16(A + ga0 + koff, &As[nb * 4096 + slab0 * 512]);
        GLOAD_LDS16(A + ga1 + koff, &As[nb * 4096 + slab0 * 512 + 512]);
        GLOAD_LDS16(B + gb0 + koff, &Bs[nb * 4096 + slab0 * 512]);
        GLOAD_LDS16(B + gb1 + koff, &Bs[nb * 4096 + slab0 * 512 + 512]);

        const ushort* as = &As[buf * 4096];
        const ushort* bs = &Bs[buf * 4096];
        bf16x8 af[4], bfv[4];
        #pragma unroll
        for (int t = 0; t < 4; t++) {
            af[t]  = *reinterpret_cast<const bf16x8*>(&as[(wm * 64 + t * 16 + fr) * 32 + chq * 8]);
            bfv[t] = *reinterpret_cast<const bf16x8*>(&bs[(wn * 64 + t * 16 + fr) * 32 + chq * 8]);
        }
        #pragma unroll
        for (int ii = 0; ii < 4; ii++)
            #pragma unroll
            for (int jj = 0; jj < 4; jj++)
                acc[ii][jj] = __builtin_amdgcn_mfma_f32_16x16x32_bf16(af[ii], bfv[jj], acc[ii][jj], 0, 0, 0);
        buf = (buf == 2) ? 0 : buf + 1;
    }
    // drain everything (incl. dummies + LDS ops) before LDS reuse in epilogue
    asm volatile("s_waitcnt vmcnt(0) lgkmcnt(0)" ::: "memory");
    asm volatile("s_barrier" ::: "memory");
}

// Fused projection GEMM: A = x_bf [NTOK,1024], B = Wcat [6144,1024].
// m-fast grid (default mapping is already XCD-friendly; see R7 note).
__global__ __launch_bounds__(256) void proj_gemm_fused(
    const ushort* __restrict__ xbf, const ushort* __restrict__ Wcat,
    const float* __restrict__ b_x, const float* __restrict__ b_g,
    const float* __restrict__ b_dt, ushort* __restrict__ u_out,
    ushort* __restrict__ g_out, float* __restrict__ dt_sum)
{
    __shared__ ushort S[24576];            // 48KB: As(3buf)|Bs(3buf); epi reuses
    ushort* As = S;
    ushort* Bs = S + 12288;
    const int tid = threadIdx.x, lane = tid & 63, w = tid >> 6;
    const int wm = w & 1, wn = w >> 1;
    const int m0 = blockIdx.x * 128, n0 = blockIdx.y * 128;   // m-fast
    const int quad = lane >> 4, fr = lane & 15;

    f32x4 acc[4][4];
    #pragma unroll
    for (int i = 0; i < 4; i++)
        #pragma unroll
        for (int j = 0; j < 4; j++)
            acc[i][j] = (f32x4){0.f, 0.f, 0.f, 0.f};

    kloop_pipe3(xbf, Wcat, D_MODEL, m0, n0, As, Bs, acc, lane, w, wm, wn);

    const int region = n0 >> 11;           // 0:u 1:g 2:dt
    const int ncb = n0 & 2047;

    if (region == 2) {
        #pragma unroll
        for (int j = 0; j < 4; j++) {
            int n = ncb + wn * 64 + j * 16 + fr;
            float bj = b_dt[n];
            float s = 0.f;
            #pragma unroll
            for (int i = 0; i < 4; i++)
                #pragma unroll
                for (int r = 0; r < 4; r++)
                    s += softplus_f(acc[i][j][r] + bj);
            s += __shfl_xor(s, 16);
            s += __shfl_xor(s, 32);
            if (lane < 16) atomicAdd(&dt_sum[n], s);
        }
    } else {
        const float* bias = region ? b_g : b_x;
        ushort* out = region ? g_out : u_out;
        ushort* Cs = S;                    // [128][128] bf16 = 32KB (fits 48KB)
        #pragma unroll
        for (int j = 0; j < 4; j++) {
            int col = wn * 64 + j * 16 + fr;
            float bj = bias[ncb + col];
            #pragma unroll
            for (int i = 0; i < 4; i++) {
                int row = wm * 64 + i * 16 + quad * 4;
                #pragma unroll
                for (int r = 0; r < 4; r++) {
                    float v = acc[i][j][r] + bj;
                    if (region) v = sigmoid_f(v);
                    Cs[(row + r) * 128 + col] = f2bf(v);
                }
            }
        }
        __syncthreads();
        #pragma unroll
        for (int k = 0; k < 8; k++) {
            int v = k * 256 + tid;
            int row = v >> 4, c = (v & 15) * 8;
            *reinterpret_cast<ushort8*>(&out[(size_t)(m0 + row) * HIDDEN + ncb + c]) =
                *reinterpret_cast<const ushort8*>(&Cs[v * 8]);
        }
    }
}

// ---------------------------------------------------------------------------
// Out projection, 64x128 tile, BK=64, pipe3 (3 bufs, vmcnt(6)). m-fast grid.
// ---------------------------------------------------------------------------
__global__ __launch_bounds__(256) void gemm_out64(
    const ushort* __restrict__ ybf, const ushort* __restrict__ Wout,
    const float* __restrict__ b_out, const float* __restrict__ x,
    float* __restrict__ resid)
{
    __shared__ ushort S[36864];            // 72KB: As 3x4096us | Bs 3x8192us
    ushort* As = S;
    ushort* Bs = S + 12288;
    const int tid = threadIdx.x, lane = tid & 63, w = tid >> 6;
    const int m0 = blockIdx.x * 64, n0 = blockIdx.y * 128;    // m-fast
    const int quad = lane >> 4, fr = lane & 15;
    const int lr8  = lane >> 3;                   // row-in-8 for staging
    const int q8   = (lane & 7) ^ (lr8 & 7);      // pre-swizzled src chunk
    const int K = HIDDEN;

    const size_t ga = (size_t)(m0 + w * 16 + lr8) * K + q8 * 8;
    const size_t gb = (size_t)(n0 + w * 32 + lr8) * K + q8 * 8;

    f32x4 acc[4][2];
    #pragma unroll
    for (int i = 0; i < 4; i++)
        #pragma unroll
        for (int j = 0; j < 2; j++)
            acc[i][j] = (f32x4){0.f, 0.f, 0.f, 0.f};

#define STAGE_OUT(KT, BUF) do {                                                   \
    const size_t ko_ = (size_t)(KT) * 64;                                         \
    GLOAD_LDS16(ybf  + ga + ko_,            &As[(BUF)*4096 + (w*2+0)*512]);       \
    GLOAD_LDS16(ybf  + ga + 8*K + ko_,      &As[(BUF)*4096 + (w*2+1)*512]);       \
    GLOAD_LDS16(Wout + gb + ko_,            &Bs[(BUF)*8192 + (w*4+0)*512]);       \
    GLOAD_LDS16(Wout + gb + 8*K + ko_,      &Bs[(BUF)*8192 + (w*4+1)*512]);       \
    GLOAD_LDS16(Wout + gb + 16*K + ko_,     &Bs[(BUF)*8192 + (w*4+2)*512]);       \
    GLOAD_LDS16(Wout + gb + 24*K + ko_,     &Bs[(BUF)*8192 + (w*4+3)*512]);       \
  } while (0)

    STAGE_OUT(0, 0);
    STAGE_OUT(1, 1);

    int buf = 0;
    for (int t = 0; t < 32; t++) {
        asm volatile("s_waitcnt vmcnt(6) lgkmcnt(0)" ::: "memory");
        asm volatile("s_barrier" ::: "memory");
        int nb = buf + 2; if (nb >= 3) nb -= 3;
        const int kt = (t + 2 < 32) ? (t + 2) : 0;    // dummy past end
        STAGE_OUT(kt, nb);

        const ushort* as = &As[buf * 4096];
        const ushort* bs = &Bs[buf * 8192];
        #pragma unroll
        for (int ks = 0; ks < 2; ks++) {
            const int ch = ((ks * 4 + quad) ^ (fr & 7)) * 8;
            bf16x8 af[4], bfv[2];
            #pragma unroll
            for (int mi = 0; mi < 4; mi++)
                af[mi] = *reinterpret_cast<const bf16x8*>(&as[(mi * 16 + fr) * 64 + ch]);
            #pragma unroll
            for (int nj = 0; nj < 2; nj++)
                bfv[nj] = *reinterpret_cast<const bf16x8*>(&bs[(w * 32 + nj * 16 + fr) * 64 + ch]);
            #pragma unroll
            for (int mi = 0; mi < 4; mi++)
                #pragma unroll
                for (int nj = 0; nj < 2; nj++)
                    acc[mi][nj] = __builtin_amdgcn_mfma_f32_16x16x32_bf16(af[mi], bfv[nj], acc[mi][nj], 0, 0, 0);
        }
        buf = (buf == 2) ? 0 : buf + 1;
    }
    asm volatile("s_waitcnt vmcnt(0) lgkmcnt(0)" ::: "memory");
    asm volatile("s_barrier" ::: "memory");
#undef STAGE_OUT

    float* Sf = (float*)S;                  // [64][128] f32 = 32KB (fits 72KB)
    #pragma unroll
    for (int nj = 0; nj < 2; nj++) {
        int col = w * 32 + nj * 16 + fr;
        float bj = b_out[n0 + col];
        #pragma unroll
        for (int mi = 0; mi < 4; mi++) {
            int row = mi * 16 + quad * 4;
            #pragma unroll
            for (int r = 0; r < 4; r++)
                Sf[(row + r) * 128 + col] = acc[mi][nj][r] + bj;
        }
    }
    __syncthreads();
    #pragma unroll
    for (int k = 0; k < 8; k++) {
        int v = k * 256 + tid;                 // float4 id, 0..2047
        int row = v >> 5, c = (v & 31) * 4;
        size_t off = (size_t)(m0 + row) * D_MODEL + n0 + c;
        float4 xa = *reinterpret_cast<const float4*>(&x[off]);
        float4 cv = *reinterpret_cast<const float4*>(&Sf[v * 4]);
        float4 o = { cv.x + xa.x, cv.y + xa.y, cv.z + xa.z, cv.w + xa.w };
        *reinterpret_cast<float4*>(&resid[off]) = o;
    }
}

__global__ __launch_bounds__(256) void dt_finalize(
    const float* __restrict__ dt_sum, const float* __restrict__ A_raw,
    const float* __restrict__ B_ssm, float* __restrict__ A_d,
    float* __restrict__ B_d, float* __restrict__ A_dL)
{
    int i = blockIdx.x * 256 + threadIdx.x;
    if (i >= HIDDEN * D_STATE) return;
    int h = i >> 4;
    float dt = dt_sum[h] * (1.0f / NTOK);
    dt = fminf(fmaxf(dt, 1e-3f), 2.0f);
    float Av = -softplus_f(A_raw[i]);
    float Ad = expf(Av * dt);
    float Bd = (Ad - 1.0f) / (Av + 1e-6f) * B_ssm[i];
    A_d[i] = Ad;
    B_d[i] = Bd;
    A_dL[i] = expf(Av * dt * CHUNK);
}

// Pass 1 (fused conv + gate + local scan): per-(b,chunk,h) thread.
__global__ __launch_bounds__(256) void scan_pass1(
    const ushort* __restrict__ u_bf, const ushort* __restrict__ g_bf,
    const float* __restrict__ conv_w, const float* __restrict__ conv_b,
    const float* __restrict__ A_d, const float* __restrict__ B_d,
    const float* __restrict__ C_ssm,
    ushort* __restrict__ ypart, float* __restrict__ states)
{
    int idx = blockIdx.x * 256 + threadIdx.x;
    int h  = idx & (HIDDEN - 1);
    int bc = idx >> 11;
    int c  = bc & (NCHUNK - 1);
    int b  = bc / NCHUNK;
    float Ad[D_STATE], Bd[D_STATE], Cv[D_STATE], st[D_STATE];
    const float4* a4 = reinterpret_cast<const float4*>(A_d  + h * D_STATE);
    const float4* b4 = reinterpret_cast<const float4*>(B_d  + h * D_STATE);
    const float4* c4 = reinterpret_cast<const float4*>(C_ssm + h * D_STATE);
    #pragma unroll
    for (int q = 0; q < 4; q++) {
        float4 av = a4[q], bv = b4[q], cv = c4[q];
        Ad[q*4+0]=av.x; Ad[q*4+1]=av.y; Ad[q*4+2]=av.z; Ad[q*4+3]=av.w;
        Bd[q*4+0]=bv.x; Bd[q*4+1]=bv.y; Bd[q*4+2]=bv.z; Bd[q*4+3]=bv.w;
        Cv[q*4+0]=cv.x; Cv[q*4+1]=cv.y; Cv[q*4+2]=cv.z; Cv[q*4+3]=cv.w;
    }
    #pragma unroll
    for (int s = 0; s < D_STATE; s++) st[s] = 0.f;

    float w0 = conv_w[h * 3 + 0], w1 = conv_w[h * 3 + 1];
    float w2 = conv_w[h * 3 + 2], cb = conv_b[h];
    const int tok0 = c * CHUNK;
    const size_t base = ((size_t)b * SEQ + tok0) * HIDDEN + h;
    float u_prev = (tok0 > 0) ? bf2f(u_bf[base - HIDDEN]) : 0.f;
    float u_cur  = bf2f(u_bf[base]);
    for (int l = 0; l < CHUNK; l++) {
        float u_next = (tok0 + l + 1 < SEQ) ? bf2f(u_bf[base + (size_t)(l + 1) * HIDDEN]) : 0.f;
        float gv = bf2f(g_bf[base + (size_t)l * HIDDEN]);
        float conv = u_prev * w0 + u_cur * w1 + u_next * w2 + cb;
        float uv = u_cur * gv + conv * (1.0f - gv);
        float y0 = 0.f, y1 = 0.f, y2 = 0.f, y3 = 0.f;
        #pragma unroll
        for (int s = 0; s < D_STATE; s += 4) {
            st[s+0] = fmaf(Ad[s+0], st[s+0], Bd[s+0] * uv);
            st[s+1] = fmaf(Ad[s+1], st[s+1], Bd[s+1] * uv);
            st[s+2] = fmaf(Ad[s+2], st[s+2], Bd[s+2] * uv);
            st[s+3] = fmaf(Ad[s+3], st[s+3], Bd[s+3] * uv);
            y0 = fmaf(st[s+0], Cv[s+0], y0);
            y1 = fmaf(st[s+1], Cv[s+1], y1);
            y2 = fmaf(st[s+2], Cv[s+2], y2);
            y3 = fmaf(st[s+3], Cv[s+3], y3);
        }
        ypart[base + (size_t)l * HIDDEN] = f2bf((y0 + y1) + (y2 + y3));
        u_prev = u_cur; u_cur = u_next;
    }
    float4* sp = reinterpret_cast<float4*>(states + ((size_t)bc * HIDDEN + h) * D_STATE);
    #pragma unroll
    for (int q = 0; q < 4; q++)
        sp[q] = (float4){st[q*4+0], st[q*4+1], st[q*4+2], st[q*4+3]};
}

// Pass 2: in-place exclusive propagation of chunk-boundary states.
// Batched 8-deep load prefetch: 8 independent loads in flight per group.
__global__ __launch_bounds__(256) void scan_pass2(
    float* __restrict__ states, const float* __restrict__ A_dL)
{
    int idx = blockIdx.x * 256 + threadIdx.x;
    int s = idx & 15;
    int h = (idx >> 4) & (HIDDEN - 1);
    int b = idx >> 15;
    float aL = A_dL[h * D_STATE + s];
    float carry = 0.f;
    const size_t cstride = (size_t)HIDDEN * D_STATE;
    float* p = states + ((size_t)b * NCHUNK * HIDDEN + h) * D_STATE + s;
    #pragma unroll 1
    for (int cb = 0; cb < NCHUNK / 8; cb++) {
        float fin[8];
        #pragma unroll
        for (int j = 0; j < 8; j++) fin[j] = p[(size_t)j * cstride];
        #pragma unroll
        for (int j = 0; j < 8; j++) {
            p[(size_t)j * cstride] = carry;
            carry = fmaf(aL, carry, fin[j]);
        }
        p += 8 * cstride;
    }
}

// Pass 3: y = ypart + sum_s C*A_d^(l+1)*s_in ; emit bf16 for the out-GEMM.
__global__ __launch_bounds__(256) void scan_pass3(
    const ushort* __restrict__ ypart, const float* __restrict__ states,
    const float* __restrict__ A_d, const float* __restrict__ C_ssm,
    ushort* __restrict__ ybf)
{
    int idx = blockIdx.x * 256 + threadIdx.x;
    int h  = idx & (HIDDEN - 1);
    int bc = idx >> 11;
    int c  = bc & (NCHUNK - 1);
    int b  = bc / NCHUNK;
    float Ad[D_STATE], t[D_STATE];
    const float* sp = states + ((size_t)bc * HIDDEN + h) * D_STATE;
    #pragma unroll
    for (int s = 0; s < D_STATE; s++) {
        float a = A_d[h * D_STATE + s];
        Ad[s] = a;
        t[s] = C_ssm[h * D_STATE + s] * a * sp[s];
    }
    const size_t base = ((size_t)b * SEQ + (size_t)c * CHUNK) * HIDDEN + h;
    for (int l = 0; l < CHUNK; l++) {
        float c0 = 0.f, c1 = 0.f;
        #pragma unroll
        for (int s = 0; s < D_STATE; s += 2) {
            c0 += t[s];
            c1 += t[s + 1];
            t[s] *= Ad[s];
            t[s + 1] *= Ad[s + 1];
        }
        ybf[base + (size_t)l * HIDDEN] = f2bf(bf2f(ypart[base + (size_t)l * HIDDEN]) + (c0 + c1));
    }
}

__global__ __launch_bounds__(256) void ln_kernel(
    const float* __restrict__ resid, const float* __restrict__ ln_g,
    const float* __restrict__ ln_b, float* __restrict__ out)
{
    int row = blockIdx.x;
    int tid = threadIdx.x;
    const float4 v = reinterpret_cast<const float4*>(resid + (size_t)row * D_MODEL)[tid];
    float s  = v.x + v.y + v.z + v.w;
    float ss = v.x * v.x + v.y * v.y + v.z * v.z + v.w * v.w;
    #pragma unroll
    for (int off = 32; off > 0; off >>= 1) {
        s  += __shfl_down(s, off);
        ss += __shfl_down(ss, off);
    }
    __shared__ float sbuf[4], ssbuf[4];
    int wid = tid >> 6, lane = tid & 63;
    if (lane == 0) { sbuf[wid] = s; ssbuf[wid] = ss; }
    __syncthreads();
    float tot  = sbuf[0] + sbuf[1] + sbuf[2] + sbuf[3];
    float tot2 = ssbuf[0] + ssbuf[1] + ssbuf[2] + ssbuf[3];
    float mean = tot * (1.0f / D_MODEL);
    float var  = tot2 * (1.0f / D_MODEL) - mean * mean;
    float rstd = rsqrtf(var + 1e-5f);
    const float4 gv = reinterpret_cast<const float4*>(ln_g)[tid];
    const float4 bv = reinterpret_cast<const float4*>(ln_b)[tid];
    float4 o;
    o.x = (v.x - mean) * rstd * gv.x + bv.x;
    o.y = (v.y - mean) * rstd * gv.y + bv.y;
    o.z = (v.z - mean) * rstd * gv.z + bv.z;
    o.w = (v.w - mean) * rstd * gv.w + bv.w;
    reinterpret_cast<float4*>(out + (size_t)row * D_MODEL)[tid] = o;
}

extern "C" void kernel_launch(void* const* d_in, const int* in_sizes, int n_in,
                              void* d_out, int out_size, void* d_ws, size_t ws_size,
                              hipStream_t stream) {
    const float* x      = (const float*)d_in[0];
    const float* W_x    = (const float*)d_in[1];
    const float* b_x    = (const float*)d_in[2];
    const float* W_g    = (const float*)d_in[3];
    const float* b_g    = (const float*)d_in[4];
    const float* conv_w = (const float*)d_in[5];
    const float* conv_b = (const float*)d_in[6];
    const float* A_raw  = (const float*)d_in[7];
    const float* B_ssm  = (const float*)d_in[8];
    const float* C_ssm  = (const float*)d_in[9];
    const float* W_dt   = (const float*)d_in[10];
    const float* b_dt   = (const float*)d_in[11];
    const float* W_out  = (const float*)d_in[12];
    const float* b_out  = (const float*)d_in[13];
    const float* ln_g   = (const float*)d_in[14];
    const float* ln_b   = (const float*)d_in[15];

    char* W = (char*)d_ws;
    ushort* arena   = (ushort*)(W);                    // 24MB: x_bf|Wcat|Wout_bf
    ushort* x_bf    = arena;                           // [4096,1024]
    ushort* Wcat    = arena + 4194304;                 // [6144,1024] (Wx|Wg|Wdt)
    ushort* Wout_bf = arena + 10485760;                // [1024,2048] (20..24MB)
    ushort* u_bf    = (ushort*)(W + (24ull << 20));    // 16MB [4096,2048] -> y_bf
    ushort* g_bf    = (ushort*)(W + (40ull << 20));    // 16MB [4096,2048]
    ushort* ypart   = (ushort*)(W + (56ull << 20));    // 16MB bf16 partial y
    float*  resid   = (float*)(W + (40ull << 20));     // 16MB, over g_bf (dead)
    // states: 16MB [B*NCHUNK,H,16] over x_bf+Wcat (0..16MB, dead after proj)
    float*  states  = (float*)(W);
    float*  dt_sum  = (float*)(W + (80ull << 20));     // 8KB
    float*  A_d     = (float*)(W + (80ull << 20) + 65536);
    float*  B_d     = (float*)(W + (80ull << 20) + 65536 + 131072);
    float*  A_dL    = (float*)(W + (80ull << 20) + 65536 + 262144);
    ushort* y_bf    = u_bf;                            // alias (u dead after pass1)

    dim3 blk(256);
    cvt_all<<<12288, blk, 0, stream>>>(x, W_x, W_g, W_dt, W_out, arena, dt_sum);

    dim3 grid_proj(NTOK / 128, 3 * HIDDEN / 128);   // (32 m, 48 n), m fastest
    proj_gemm_fused<<<grid_proj, blk, 0, stream>>>(x_bf, Wcat, b_x, b_g, b_dt,
                                                   u_bf, g_bf, dt_sum);
    dt_finalize<<<(HIDDEN * D_STATE) / 256, blk, 0, stream>>>(dt_sum, A_raw, B_ssm,
                                                              A_d, B_d, A_dL);
    scan_pass1<<<(BATCH * NCHUNK * HIDDEN) / 256, blk, 0, stream>>>(
        u_bf, g_bf, conv_w, conv_b, A_d, B_d, C_ssm, ypart, states);
    scan_pass2<<<(BATCH * HIDDEN * D_STATE) / 256, blk, 0, stream>>>(states, A_dL);
    scan_pass3<<<(BATCH * NCHUNK * HIDDEN) / 256, blk, 0, stream>>>(ypart, states, A_d,
                                                                    C_ssm, y_bf);
    dim3 grid_out(NTOK / 64, D_MODEL / 128);        // (64 m, 8 n), m fastest
    gemm_out64<<<grid_out, blk, 0, stream>>>(y_bf, Wout_bf, b_out, x, resid);
    ln_kernel<<<NTOK, blk, 0, stream>>>(resid, ln_g, ln_b, (float*)d_out);
}